// Round 3
// baseline (290.071 us; speedup 1.0000x reference)
//
#include <hip/hip_runtime.h>
#include <hip/hip_bf16.h>

#define TOK 16384
#define HD  1024
#define DD  256
#define NE  8

typedef __attribute__((ext_vector_type(8))) short short8;
typedef __attribute__((ext_vector_type(4))) float floatx4;
typedef unsigned short u16;

static __device__ __forceinline__ u16 f2bf(float f) {
  __hip_bfloat16 h = __float2bfloat16(f);
  return *reinterpret_cast<u16*>(&h);
}
// convert 8 consecutive fp32 (16B-aligned) -> bf16 short8
static __device__ __forceinline__ short8 cvt8(const float* p) {
  float4 a = *(const float4*)p;
  float4 b = *(const float4*)(p + 4);
  u16 t[8] = {f2bf(a.x), f2bf(a.y), f2bf(a.z), f2bf(a.w),
              f2bf(b.x), f2bf(b.y), f2bf(b.z), f2bf(b.w)};
  return *(short8*)t;
}

// load one 64-K fragment set (2 k-halves of 32) straight from global (L2/L3)
static __device__ __forceinline__ void load_set(
    short8 (&Sa)[2][4], short8 (&Sb)[2][4],
    const u16* const (&aB)[4], const u16* const (&bB)[4], int kk) {
#pragma unroll
  for (int h = 0; h < 2; ++h) {
#pragma unroll
    for (int m = 0; m < 4; ++m) Sa[h][m] = *(const short8*)(aB[m] + kk + h * 32);
#pragma unroll
    for (int j = 0; j < 4; ++j) Sb[h][j] = *(const short8*)(bB[j] + kk + h * 32);
  }
}
static __device__ __forceinline__ void mfma_set(
    floatx4 (&acc)[4][4], short8 (&Sa)[2][4], short8 (&Sb)[2][4]) {
#pragma unroll
  for (int h = 0; h < 2; ++h)
#pragma unroll
    for (int m = 0; m < 4; ++m)
#pragma unroll
      for (int j = 0; j < 4; ++j)
        acc[m][j] = __builtin_amdgcn_mfma_f32_16x16x32_bf16(Sa[h][m], Sb[h][j], acc[m][j], 0, 0, 0);
}

// ---- prep: weight transpose->bf16 (blocks 0..1535) + router (blocks 1536..2559)
// wg,wu: [E][1024][256] -> bf16 [E][256][1024]; wd: [E][256][1024] -> bf16 [E][1024][256]
// router: 16 tokens/block, 4 tokens per wave processed in ONE gw pass
//         (gw L2 traffic /4, one x-load latency per 4 tokens); emits bf16 x.
__global__ __launch_bounds__(256) void prep_kernel(
    const float* __restrict__ wg, const float* __restrict__ wu,
    const float* __restrict__ wd, const float* __restrict__ x,
    const float* __restrict__ gw,
    u16* __restrict__ wgT, u16* __restrict__ wuT, u16* __restrict__ wdT,
    u16* __restrict__ xbf,
    int* __restrict__ counts, int* __restrict__ tlist)
{
  __shared__ u16 tile[64][72];
  __shared__ int sexp[16];
  __shared__ int sbase[NE];
  int bid = blockIdx.x;
  int tid = threadIdx.x;

  if (bid < 1536) {
    const float* src; u16* dst; int R, C;
    if (bid < 512)       { src = wg; dst = wgT; R = HD; C = DD; }
    else if (bid < 1024) { src = wu; dst = wuT; R = HD; C = DD; bid -= 512; }
    else                 { src = wd; dst = wdT; R = DD; C = HD; bid -= 1024; }
    int e = bid >> 6, t = bid & 63;
    int ntc = C >> 6;
    int tr = t / ntc, tc = t % ntc;
    int r = tid >> 2, c0 = (tid & 3) * 16;
    const float* s = src + (size_t)e * R * C + (size_t)(tr * 64 + r) * C + tc * 64 + c0;
    *(short8*)&tile[r][c0]     = cvt8(s);
    *(short8*)&tile[r][c0 + 8] = cvt8(s + 8);
    __syncthreads();
    int c = tid >> 2, r0 = (tid & 3) * 16;
    alignas(16) u16 buf[16];
    for (int j = 0; j < 16; ++j) buf[j] = tile[r0 + j][c];
    u16* d = dst + (size_t)e * R * C + (size_t)(tc * 64 + c) * R + tr * 64 + r0;
    *(float4*)(d)     = *(const float4*)&buf[0];
    *(float4*)(d + 8) = *(const float4*)&buf[8];
    return;
  }

  // ---- router: 4 tokens per wave, batched through one gw pass
  int lane = tid & 63, wave = tid >> 6;
  int tok0 = (bid - 1536) * 16 + wave * 4;
  float4 xr[4][4];
#pragma unroll
  for (int t = 0; t < 4; ++t) {
    const float* xp = x + (size_t)(tok0 + t) * HD + lane * 16;
    xr[t][0] = *(const float4*)xp;
    xr[t][1] = *(const float4*)(xp + 4);
    xr[t][2] = *(const float4*)(xp + 8);
    xr[t][3] = *(const float4*)(xp + 12);
  }
#pragma unroll
  for (int t = 0; t < 4; ++t) {
    alignas(16) u16 b[16] = {
      f2bf(xr[t][0].x), f2bf(xr[t][0].y), f2bf(xr[t][0].z), f2bf(xr[t][0].w),
      f2bf(xr[t][1].x), f2bf(xr[t][1].y), f2bf(xr[t][1].z), f2bf(xr[t][1].w),
      f2bf(xr[t][2].x), f2bf(xr[t][2].y), f2bf(xr[t][2].z), f2bf(xr[t][2].w),
      f2bf(xr[t][3].x), f2bf(xr[t][3].y), f2bf(xr[t][3].z), f2bf(xr[t][3].w)};
    u16* xd = xbf + (size_t)(tok0 + t) * HD + lane * 16;
    *(float4*)xd       = *(const float4*)&b[0];
    *(float4*)(xd + 8) = *(const float4*)&b[8];
  }
  float acc[4][NE];
#pragma unroll
  for (int e = 0; e < NE; ++e) {
    const float* gp = gw + e * HD + lane * 16;
    float4 g0 = *(const float4*)gp,       g1 = *(const float4*)(gp + 4);
    float4 g2 = *(const float4*)(gp + 8), g3 = *(const float4*)(gp + 12);
#pragma unroll
    for (int t = 0; t < 4; ++t) {
      acc[t][e] = xr[t][0].x*g0.x + xr[t][0].y*g0.y + xr[t][0].z*g0.z + xr[t][0].w*g0.w
                + xr[t][1].x*g1.x + xr[t][1].y*g1.y + xr[t][1].z*g1.z + xr[t][1].w*g1.w
                + xr[t][2].x*g2.x + xr[t][2].y*g2.y + xr[t][2].z*g2.z + xr[t][2].w*g2.w
                + xr[t][3].x*g3.x + xr[t][3].y*g3.y + xr[t][3].z*g3.z + xr[t][3].w*g3.w;
    }
  }
  for (int off = 32; off >= 1; off >>= 1)
#pragma unroll
    for (int t = 0; t < 4; ++t)
#pragma unroll
      for (int e = 0; e < NE; ++e) acc[t][e] += __shfl_xor(acc[t][e], off, 64);
  if (lane == 0) {
#pragma unroll
    for (int t = 0; t < 4; ++t) {
      int be = 0; float bv = acc[t][0];
      for (int e = 1; e < NE; ++e) if (acc[t][e] > bv) { bv = acc[t][e]; be = e; }
      sexp[wave * 4 + t] = be;
    }
  }
  __syncthreads();
  if (tid < NE) {
    int c = 0;
    for (int i = 0; i < 16; ++i) c += (sexp[i] == tid) ? 1 : 0;
    sbase[tid] = c ? atomicAdd(&counts[tid], c) : 0;
  }
  __syncthreads();
  if (tid < 16) {
    int e = sexp[tid], rank = 0;
    for (int i = 0; i < tid; ++i) rank += (sexp[i] == e) ? 1 : 0;
    tlist[e * TOK + sbase[e] + rank] = (bid - 1536) * 16 + tid;
  }
}

// ---- gemm1: gathered xbf(bf16) @ [g-half ++ u-half], epilogue relu(g)^2*u -> inter bf16
// flat grid 4096: e=bid&7 (XCD locality), half=(bid>>3)&1, tile=bid>>4 (64 tokens)
// LDS-FREE K-loop: A/B fragments loaded per-lane straight from L3/L2
// (wave reads 16 rows x 64B contiguous per fragment = line-coalesced).
// No barriers in the loop; P/Q 64-K register double-buffer.
__global__ __launch_bounds__(256, 2) void gemm1_kernel(
    const u16* __restrict__ xbf, const u16* __restrict__ wgT,
    const u16* __restrict__ wuT,
    const int* __restrict__ counts, const int* __restrict__ tlist,
    u16* __restrict__ inter)
{
  int bid = blockIdx.x;
  int e = bid & 7, half = (bid >> 3) & 1, tile = bid >> 4;
  int cnt = counts[e];
  int row0 = tile * 64;
  if (row0 >= cnt) return;

  __shared__ int stok[64];
  int tid = threadIdx.x, lane = tid & 63, wave = tid >> 6;
  if (tid < 64) {
    int r = row0 + tid;
    stok[tid] = tlist[e * TOK + (r < cnt ? r : cnt - 1)];
  }
  __syncthreads();
  int rmax = cnt - row0; if (rmax > 64) rmax = 64;

  int col = lane & 15, quad = lane >> 4;

  const u16* aB[4];
#pragma unroll
  for (int m = 0; m < 4; ++m)
    aB[m] = xbf + (size_t)stok[m * 16 + col] * HD + quad * 8;
  int nb = e * DD + half * 128 + wave * 32 + col;   // B row base (j=0)
  const u16* bB[4];
  bB[0] = wgT + (size_t)nb * HD + quad * 8;
  bB[1] = wgT + (size_t)(nb + 16) * HD + quad * 8;
  bB[2] = wuT + (size_t)nb * HD + quad * 8;
  bB[3] = wuT + (size_t)(nb + 16) * HD + quad * 8;

  floatx4 acc[4][4];
  floatx4 zz = {0.f, 0.f, 0.f, 0.f};
#pragma unroll
  for (int m = 0; m < 4; ++m)
#pragma unroll
    for (int j = 0; j < 4; ++j) acc[m][j] = zz;

  short8 Pa[2][4], Pb[2][4], Qa[2][4], Qb[2][4];
  load_set(Pa, Pb, aB, bB, 0);
  load_set(Qa, Qb, aB, bB, 64);
  for (int k0 = 0; k0 < HD; k0 += 128) {
    mfma_set(acc, Pa, Pb);
    if (k0 + 128 < HD) load_set(Pa, Pb, aB, bB, k0 + 128);
    mfma_set(acc, Qa, Qb);
    if (k0 + 192 < HD) load_set(Qa, Qb, aB, bB, k0 + 192);
  }

#pragma unroll
  for (int m = 0; m < 4; ++m)
#pragma unroll
    for (int jj = 0; jj < 2; ++jj)
#pragma unroll
      for (int r = 0; r < 4; ++r) {
        int row = m * 16 + quad * 4 + r;     // C layout: col=lane&15, row=quad*4+reg
        if (row < rmax) {
          float g = acc[m][jj][r]; g = g > 0.f ? g : 0.f;
          float u = acc[m][jj + 2][r];
          inter[(size_t)stok[row] * DD + half * 128 + wave * 32 + jj * 16 + col] = f2bf(g * g * u);
        }
      }
}

// ---- gemm2: gathered inter(bf16) @ wdT -> out fp32 (LDS-staged coalesced stores)
// flat grid 8192: e=bid&7, q=(bid>>3)&3 (256-col quarter), tile=bid>>5 (64 tokens)
// Same LDS-free direct-fragment K-loop (K=256 -> 2 P/Q bodies).
__global__ __launch_bounds__(256, 2) void gemm2_kernel(
    const u16* __restrict__ inter, const u16* __restrict__ wdT,
    const int* __restrict__ counts, const int* __restrict__ tlist,
    float* __restrict__ out)
{
  int bid = blockIdx.x;
  int e = bid & 7, q = (bid >> 3) & 3, tile = bid >> 5;
  int cnt = counts[e];
  int row0 = tile * 64;
  if (row0 >= cnt) return;
  int n0 = q * 256;

  __shared__ int stok[64];
  __shared__ float st[16][260];   // epilogue store staging

  int tid = threadIdx.x, lane = tid & 63, wave = tid >> 6;
  if (tid < 64) {
    int r = row0 + tid;
    stok[tid] = tlist[e * TOK + (r < cnt ? r : cnt - 1)];
  }
  __syncthreads();
  int rmax = cnt - row0; if (rmax > 64) rmax = 64;

  int col = lane & 15, quad = lane >> 4;

  const u16* aB[4];
#pragma unroll
  for (int m = 0; m < 4; ++m)
    aB[m] = inter + (size_t)stok[m * 16 + col] * DD + quad * 8;
  int nb = e * HD + n0 + wave * 64 + col;
  const u16* bB[4];
#pragma unroll
  for (int j = 0; j < 4; ++j)
    bB[j] = wdT + (size_t)(nb + j * 16) * DD + quad * 8;

  floatx4 acc[4][4];
  floatx4 zz = {0.f, 0.f, 0.f, 0.f};
#pragma unroll
  for (int m = 0; m < 4; ++m)
#pragma unroll
    for (int j = 0; j < 4; ++j) acc[m][j] = zz;

  short8 Pa[2][4], Pb[2][4], Qa[2][4], Qb[2][4];
  load_set(Pa, Pb, aB, bB, 0);
  load_set(Qa, Qb, aB, bB, 64);
  for (int k0 = 0; k0 < DD; k0 += 128) {
    mfma_set(acc, Pa, Pb);
    if (k0 + 128 < DD) load_set(Pa, Pb, aB, bB, k0 + 128);
    mfma_set(acc, Qa, Qb);
    if (k0 + 192 < DD) load_set(Qa, Qb, aB, bB, k0 + 192);
  }

  // epilogue: 16 rows x 256 fp32 at a time through LDS -> 1KB/row coalesced stores
  for (int m = 0; m < 4; ++m) {
    __syncthreads();
#pragma unroll
    for (int j = 0; j < 4; ++j)
#pragma unroll
      for (int r = 0; r < 4; ++r)
        st[quad * 4 + r][wave * 64 + j * 16 + col] = acc[m][j][r];
    __syncthreads();
#pragma unroll
    for (int i = 0; i < 4; ++i) {
      int id = i * 256 + tid;
      int r = id >> 6, c4 = (id & 63) * 4;
      int row = m * 16 + r;
      if (row < rmax)
        *(float4*)(out + (size_t)stok[row] * HD + n0 + c4) = *(const float4*)&st[r][c4];
    }
  }
}

// ---------------- launch ---------------------------------------------------
extern "C" void kernel_launch(void* const* d_in, const int* in_sizes, int n_in,
                              void* d_out, int out_size, void* d_ws, size_t ws_size,
                              hipStream_t stream) {
  const float* x  = (const float*)d_in[0];
  const float* gw = (const float*)d_in[1];
  const float* wg = (const float*)d_in[2];
  const float* wu = (const float*)d_in[3];
  const float* wd = (const float*)d_in[4];
  float* out = (float*)d_out;

  char* ws = (char*)d_ws;
  int* counts = (int*)ws;                        // 256 B
  int* tlist  = (int*)(ws + 256);                // 512 KB
  u16* wgT   = (u16*)(ws + 524544);              // 4 MB
  u16* wuT   = wgT + (size_t)NE * DD * HD;       // 4 MB
  u16* wdT   = wuT + (size_t)NE * DD * HD;       // 4 MB
  u16* inter = wdT + (size_t)NE * HD * DD;       // 8 MB; total ~20.5 MiB
  // bf16 x staged in d_out (33.5 MB of 67 MB): written by prep, read by gemm1,
  // then fully overwritten by gemm2's stores (stream-ordered, safe).
  u16* xbf   = (u16*)d_out;

  hipMemsetAsync(counts, 0, NE * sizeof(int), stream);
  prep_kernel<<<1536 + TOK / 16, 256, 0, stream>>>(wg, wu, wd, x, gw,
                                                   wgT, wuT, wdT, xbf, counts, tlist);
  gemm1_kernel<<<4096, 256, 0, stream>>>(xbf, wgT, wuT, counts, tlist, inter);
  gemm2_kernel<<<8192, 256, 0, stream>>>(inter, wdT, counts, tlist, out);
}

// Round 4
// 216.588 us; speedup vs baseline: 1.3393x; 1.3393x over previous
//
#include <hip/hip_runtime.h>
#include <hip/hip_bf16.h>

#define TOK 16384
#define HD  1024
#define DD  256
#define NE  8

typedef __attribute__((ext_vector_type(8))) short short8;
typedef __attribute__((ext_vector_type(4))) float floatx4;
typedef unsigned short u16;

static __device__ __forceinline__ u16 f2bf(float f) {
  __hip_bfloat16 h = __float2bfloat16(f);
  return *reinterpret_cast<u16*>(&h);
}
// convert 8 consecutive fp32 (16B-aligned) -> bf16 short8
static __device__ __forceinline__ short8 cvt8(const float* p) {
  float4 a = *(const float4*)p;
  float4 b = *(const float4*)(p + 4);
  u16 t[8] = {f2bf(a.x), f2bf(a.y), f2bf(a.z), f2bf(a.w),
              f2bf(b.x), f2bf(b.y), f2bf(b.z), f2bf(b.w)};
  return *(short8*)t;
}

// async direct global->LDS: wave writes lds_base + lane*16 (1KB/instr),
// per-lane global source (pre-swizzled upstream).
static __device__ __forceinline__ void gl16(const u16* g, u16* l) {
  __builtin_amdgcn_global_load_lds(
      (const __attribute__((address_space(1))) void*)g,
      (__attribute__((address_space(3))) void*)l, 16, 0, 0);
}

// ---- prep: weight transpose->bf16 (blocks 0..1535) + router (blocks 1536..2559)
__global__ __launch_bounds__(256) void prep_kernel(
    const float* __restrict__ wg, const float* __restrict__ wu,
    const float* __restrict__ wd, const float* __restrict__ x,
    const float* __restrict__ gw,
    u16* __restrict__ wgT, u16* __restrict__ wuT, u16* __restrict__ wdT,
    u16* __restrict__ xbf,
    int* __restrict__ counts, int* __restrict__ tlist)
{
  __shared__ u16 tile[64][72];
  __shared__ int sexp[16];
  __shared__ int sbase[NE];
  int bid = blockIdx.x;
  int tid = threadIdx.x;

  if (bid < 1536) {
    const float* src; u16* dst; int R, C;
    if (bid < 512)       { src = wg; dst = wgT; R = HD; C = DD; }
    else if (bid < 1024) { src = wu; dst = wuT; R = HD; C = DD; bid -= 512; }
    else                 { src = wd; dst = wdT; R = DD; C = HD; bid -= 1024; }
    int e = bid >> 6, t = bid & 63;
    int ntc = C >> 6;
    int tr = t / ntc, tc = t % ntc;
    int r = tid >> 2, c0 = (tid & 3) * 16;
    const float* s = src + (size_t)e * R * C + (size_t)(tr * 64 + r) * C + tc * 64 + c0;
    *(short8*)&tile[r][c0]     = cvt8(s);
    *(short8*)&tile[r][c0 + 8] = cvt8(s + 8);
    __syncthreads();
    int c = tid >> 2, r0 = (tid & 3) * 16;
    alignas(16) u16 buf[16];
    for (int j = 0; j < 16; ++j) buf[j] = tile[r0 + j][c];
    u16* d = dst + (size_t)e * R * C + (size_t)(tc * 64 + c) * R + tr * 64 + r0;
    *(float4*)(d)     = *(const float4*)&buf[0];
    *(float4*)(d + 8) = *(const float4*)&buf[8];
    return;
  }

  // ---- router: 4 tokens per wave, batched through one gw pass
  int lane = tid & 63, wave = tid >> 6;
  int tok0 = (bid - 1536) * 16 + wave * 4;
  float4 xr[4][4];
#pragma unroll
  for (int t = 0; t < 4; ++t) {
    const float* xp = x + (size_t)(tok0 + t) * HD + lane * 16;
    xr[t][0] = *(const float4*)xp;
    xr[t][1] = *(const float4*)(xp + 4);
    xr[t][2] = *(const float4*)(xp + 8);
    xr[t][3] = *(const float4*)(xp + 12);
  }
#pragma unroll
  for (int t = 0; t < 4; ++t) {
    alignas(16) u16 b[16] = {
      f2bf(xr[t][0].x), f2bf(xr[t][0].y), f2bf(xr[t][0].z), f2bf(xr[t][0].w),
      f2bf(xr[t][1].x), f2bf(xr[t][1].y), f2bf(xr[t][1].z), f2bf(xr[t][1].w),
      f2bf(xr[t][2].x), f2bf(xr[t][2].y), f2bf(xr[t][2].z), f2bf(xr[t][2].w),
      f2bf(xr[t][3].x), f2bf(xr[t][3].y), f2bf(xr[t][3].z), f2bf(xr[t][3].w)};
    u16* xd = xbf + (size_t)(tok0 + t) * HD + lane * 16;
    *(float4*)xd       = *(const float4*)&b[0];
    *(float4*)(xd + 8) = *(const float4*)&b[8];
  }
  float acc[4][NE];
#pragma unroll
  for (int e = 0; e < NE; ++e) {
    const float* gp = gw + e * HD + lane * 16;
    float4 g0 = *(const float4*)gp,       g1 = *(const float4*)(gp + 4);
    float4 g2 = *(const float4*)(gp + 8), g3 = *(const float4*)(gp + 12);
#pragma unroll
    for (int t = 0; t < 4; ++t) {
      acc[t][e] = xr[t][0].x*g0.x + xr[t][0].y*g0.y + xr[t][0].z*g0.z + xr[t][0].w*g0.w
                + xr[t][1].x*g1.x + xr[t][1].y*g1.y + xr[t][1].z*g1.z + xr[t][1].w*g1.w
                + xr[t][2].x*g2.x + xr[t][2].y*g2.y + xr[t][2].z*g2.z + xr[t][2].w*g2.w
                + xr[t][3].x*g3.x + xr[t][3].y*g3.y + xr[t][3].z*g3.z + xr[t][3].w*g3.w;
    }
  }
  for (int off = 32; off >= 1; off >>= 1)
#pragma unroll
    for (int t = 0; t < 4; ++t)
#pragma unroll
      for (int e = 0; e < NE; ++e) acc[t][e] += __shfl_xor(acc[t][e], off, 64);
  if (lane == 0) {
#pragma unroll
    for (int t = 0; t < 4; ++t) {
      int be = 0; float bv = acc[t][0];
      for (int e = 1; e < NE; ++e) if (acc[t][e] > bv) { bv = acc[t][e]; be = e; }
      sexp[wave * 4 + t] = be;
    }
  }
  __syncthreads();
  if (tid < NE) {
    int c = 0;
    for (int i = 0; i < 16; ++i) c += (sexp[i] == tid) ? 1 : 0;
    sbase[tid] = c ? atomicAdd(&counts[tid], c) : 0;
  }
  __syncthreads();
  if (tid < 16) {
    int e = sexp[tid], rank = 0;
    for (int i = 0; i < tid; ++i) rank += (sexp[i] == e) ? 1 : 0;
    tlist[e * TOK + sbase[e] + rank] = (bid - 1536) * 16 + tid;
  }
}

// Swizzle scheme (both GEMMs): LDS tiles are linear [rows][32] bf16 (64B rows).
// Physical 16B slot s at row r holds logical slot s ^ ((r>>1)&3)  (bijective).
// Stage side: lane i covers row chunkbase + (i>>2), slot (i&3); since chunk
// bases are multiples of 16, source elem offset = ((i&3)^((i>>3)&3))*8 for all
// chunks. Read side: fragment row base+col (base % 16 == 0), k-group 'quad' ->
// physical slot quad ^ ((col>>1)&3). Spreads 8 rows over all 8 bank positions.

// ---- gemm1: gathered xbf(bf16) @ [g 128 rows ++ u 128 rows] -> inter bf16
// grid 4096: e=bid&7 (XCD L2 locality), half=(bid>>3)&1, tile=bid>>4 (64 tok)
// K-loop: global_load_lds(16B) double-buffered, ONE barrier per K32 step.
__global__ __launch_bounds__(256) void gemm1_kernel(
    const u16* __restrict__ xbf, const u16* __restrict__ wgT,
    const u16* __restrict__ wuT,
    const int* __restrict__ counts, const int* __restrict__ tlist,
    u16* __restrict__ inter)
{
  int bid = blockIdx.x;
  int e = bid & 7, half = (bid >> 3) & 1, tile = bid >> 4;
  int cnt = counts[e];
  int row0 = tile * 64;
  if (row0 >= cnt) return;

  __shared__ int stok[64];
  __shared__ __align__(16) u16 xA[2][64 * 32];    // 2 x 4KB
  __shared__ __align__(16) u16 sB[2][256 * 32];   // 2 x 16KB

  int tid = threadIdx.x, lane = tid & 63, wave = tid >> 6;
  if (tid < 64) {
    int r = row0 + tid;
    stok[tid] = tlist[e * TOK + (r < cnt ? r : cnt - 1)];
  }
  __syncthreads();
  int rmax = cnt - row0; if (rmax > 64) rmax = 64;

  int col = lane & 15, quad = lane >> 4;
  int soff = ((lane & 3) ^ ((lane >> 3) & 3)) * 8;  // staging src swizzle
  int rsub = lane >> 2;                             // row within 16-row chunk
  int xsl8 = (quad ^ ((col >> 1) & 3)) * 8;         // read-side swizzle

  // per-lane staging sources
  const u16* aS = xbf + (size_t)stok[wave * 16 + rsub] * HD + soff;
  const u16* bS[4];
#pragma unroll
  for (int j = 0; j < 4; ++j) {
    int r = wave * 64 + j * 16 + rsub;              // 0..255
    bS[j] = (r < 128)
        ? (wgT + ((size_t)e * DD + half * 128 + r) * HD + soff)
        : (wuT + ((size_t)e * DD + half * 128 + (r - 128)) * HD + soff);
  }

  floatx4 acc[4][4];
  floatx4 zz = {0.f, 0.f, 0.f, 0.f};
#pragma unroll
  for (int m = 0; m < 4; ++m)
#pragma unroll
    for (int j = 0; j < 4; ++j) acc[m][j] = zz;

  // prologue: stage K-step 0 into buffer 0
  gl16(aS, &xA[0][wave * 512]);
#pragma unroll
  for (int j = 0; j < 4; ++j) gl16(bS[j], &sB[0][(wave * 4 + j) * 512]);
  __syncthreads();

  for (int t = 0; t < HD / 32; ++t) {
    int b = t & 1;
    if (t + 1 < HD / 32) {                          // stage next K-step
      int k1 = (t + 1) * 32;
      gl16(aS + k1, &xA[b ^ 1][wave * 512]);
#pragma unroll
      for (int j = 0; j < 4; ++j) gl16(bS[j] + k1, &sB[b ^ 1][(wave * 4 + j) * 512]);
    }
    short8 af[4], bfr[4];
#pragma unroll
    for (int m = 0; m < 4; ++m)
      af[m] = *(const short8*)&xA[b][(m * 16 + col) * 32 + xsl8];
    bfr[0] = *(const short8*)&sB[b][(wave * 32 + col) * 32 + xsl8];
    bfr[1] = *(const short8*)&sB[b][(wave * 32 + 16 + col) * 32 + xsl8];
    bfr[2] = *(const short8*)&sB[b][(128 + wave * 32 + col) * 32 + xsl8];
    bfr[3] = *(const short8*)&sB[b][(128 + wave * 32 + 16 + col) * 32 + xsl8];
#pragma unroll
    for (int m = 0; m < 4; ++m)
#pragma unroll
      for (int j = 0; j < 4; ++j)
        acc[m][j] = __builtin_amdgcn_mfma_f32_16x16x32_bf16(af[m], bfr[j], acc[m][j], 0, 0, 0);
    __syncthreads();   // drains gload_lds (vmcnt) + ds_reads (lgkm) for swap
  }

#pragma unroll
  for (int m = 0; m < 4; ++m)
#pragma unroll
    for (int jj = 0; jj < 2; ++jj)
#pragma unroll
      for (int r = 0; r < 4; ++r) {
        int row = m * 16 + quad * 4 + r;     // C layout: col=lane&15, row=quad*4+reg
        if (row < rmax) {
          float g = acc[m][jj][r]; g = g > 0.f ? g : 0.f;
          float u = acc[m][jj + 2][r];
          inter[(size_t)stok[row] * DD + half * 128 + wave * 32 + jj * 16 + col] = f2bf(g * g * u);
        }
      }
}

// ---- gemm2: gathered inter(bf16) @ wdT quarter -> out fp32
// grid 8192: e=bid&7, q=(bid>>3)&3 (256 HD-cols), tile=bid>>5 (64 tok)
// Same gload_lds double-buffered K-loop (8 steps).
__global__ __launch_bounds__(256) void gemm2_kernel(
    const u16* __restrict__ inter, const u16* __restrict__ wdT,
    const int* __restrict__ counts, const int* __restrict__ tlist,
    float* __restrict__ out)
{
  int bid = blockIdx.x;
  int e = bid & 7, q = (bid >> 3) & 3, tile = bid >> 5;
  int cnt = counts[e];
  int row0 = tile * 64;
  if (row0 >= cnt) return;
  int n0 = q * 256;

  __shared__ int stok[64];
  __shared__ __align__(16) u16 xA[2][64 * 32];    // 2 x 4KB
  __shared__ __align__(16) u16 sB[2][256 * 32];   // 2 x 16KB; epilogue reuse
  float (*st)[260] = (float(*)[260])&sB[0][0];    // 16*260*4 = 16640B < 32KB

  int tid = threadIdx.x, lane = tid & 63, wave = tid >> 6;
  if (tid < 64) {
    int r = row0 + tid;
    stok[tid] = tlist[e * TOK + (r < cnt ? r : cnt - 1)];
  }
  __syncthreads();
  int rmax = cnt - row0; if (rmax > 64) rmax = 64;

  int col = lane & 15, quad = lane >> 4;
  int soff = ((lane & 3) ^ ((lane >> 3) & 3)) * 8;
  int rsub = lane >> 2;
  int xsl8 = (quad ^ ((col >> 1) & 3)) * 8;

  const u16* aS = inter + (size_t)stok[wave * 16 + rsub] * DD + soff;
  const u16* bS[4];
#pragma unroll
  for (int j = 0; j < 4; ++j) {
    int r = wave * 64 + j * 16 + rsub;              // 0..255
    bS[j] = wdT + ((size_t)e * HD + n0 + r) * DD + soff;
  }

  floatx4 acc[4][4];
  floatx4 zz = {0.f, 0.f, 0.f, 0.f};
#pragma unroll
  for (int m = 0; m < 4; ++m)
#pragma unroll
    for (int j = 0; j < 4; ++j) acc[m][j] = zz;

  gl16(aS, &xA[0][wave * 512]);
#pragma unroll
  for (int j = 0; j < 4; ++j) gl16(bS[j], &sB[0][(wave * 4 + j) * 512]);
  __syncthreads();

  for (int t = 0; t < DD / 32; ++t) {
    int b = t & 1;
    if (t + 1 < DD / 32) {
      int k1 = (t + 1) * 32;
      gl16(aS + k1, &xA[b ^ 1][wave * 512]);
#pragma unroll
      for (int j = 0; j < 4; ++j) gl16(bS[j] + k1, &sB[b ^ 1][(wave * 4 + j) * 512]);
    }
    short8 af[4], bfr[4];
#pragma unroll
    for (int m = 0; m < 4; ++m)
      af[m] = *(const short8*)&xA[b][(m * 16 + col) * 32 + xsl8];
#pragma unroll
    for (int j = 0; j < 4; ++j)
      bfr[j] = *(const short8*)&sB[b][(wave * 64 + j * 16 + col) * 32 + xsl8];
#pragma unroll
    for (int m = 0; m < 4; ++m)
#pragma unroll
      for (int j = 0; j < 4; ++j)
        acc[m][j] = __builtin_amdgcn_mfma_f32_16x16x32_bf16(af[m], bfr[j], acc[m][j], 0, 0, 0);
    __syncthreads();
  }

  // epilogue: 16 rows x 256 fp32 at a time through LDS -> coalesced stores
  for (int m = 0; m < 4; ++m) {
    __syncthreads();
#pragma unroll
    for (int j = 0; j < 4; ++j)
#pragma unroll
      for (int r = 0; r < 4; ++r)
        st[quad * 4 + r][wave * 64 + j * 16 + col] = acc[m][j][r];
    __syncthreads();
#pragma unroll
    for (int i = 0; i < 4; ++i) {
      int id = i * 256 + tid;
      int r = id >> 6, c4 = (id & 63) * 4;
      int row = m * 16 + r;
      if (row < rmax)
        *(float4*)(out + (size_t)stok[row] * HD + n0 + c4) = *(const float4*)&st[r][c4];
    }
  }
}

// ---------------- launch ---------------------------------------------------
extern "C" void kernel_launch(void* const* d_in, const int* in_sizes, int n_in,
                              void* d_out, int out_size, void* d_ws, size_t ws_size,
                              hipStream_t stream) {
  const float* x  = (const float*)d_in[0];
  const float* gw = (const float*)d_in[1];
  const float* wg = (const float*)d_in[2];
  const float* wu = (const float*)d_in[3];
  const float* wd = (const float*)d_in[4];
  float* out = (float*)d_out;

  char* ws = (char*)d_ws;
  int* counts = (int*)ws;                        // 256 B
  int* tlist  = (int*)(ws + 256);                // 512 KB
  u16* wgT   = (u16*)(ws + 524544);              // 4 MB
  u16* wuT   = wgT + (size_t)NE * DD * HD;       // 4 MB
  u16* wdT   = wuT + (size_t)NE * DD * HD;       // 4 MB
  u16* inter = wdT + (size_t)NE * HD * DD;       // 8 MB; total ~20.5 MiB
  // bf16 x staged in d_out: written by prep, read by gemm1, then fully
  // overwritten by gemm2's stores (stream-ordered, safe).
  u16* xbf   = (u16*)d_out;

  hipMemsetAsync(counts, 0, NE * sizeof(int), stream);
  prep_kernel<<<1536 + TOK / 16, 256, 0, stream>>>(wg, wu, wd, x, gw,
                                                   wgT, wuT, wdT, xbf, counts, tlist);
  gemm1_kernel<<<4096, 256, 0, stream>>>(xbf, wgT, wuT, counts, tlist, inter);
  gemm2_kernel<<<8192, 256, 0, stream>>>(inter, wdT, counts, tlist, out);
}